// Round 7
// baseline (209.852 us; speedup 1.0000x reference)
//
#include <hip/hip_runtime.h>
#include <hip/hip_bf16.h>

#define B_ 8
#define S1_ 2048
#define S2_ 2048
#define D_ 512
#define F_ 256

typedef __attribute__((ext_vector_type(4))) float f32x4;
typedef __attribute__((ext_vector_type(8))) short s16x8;
typedef __attribute__((ext_vector_type(4))) short s16x4;

__device__ __forceinline__ short f2bf(float x) {
  union { float f; unsigned u; } v; v.f = x;
  unsigned r = v.u + 0x7fffu + ((v.u >> 16) & 1u);
  return (short)(r >> 16);
}

__device__ __forceinline__ int pk2bf(float a, float b) {
  union { __hip_bfloat162 h; int i; } u;
  u.h = __float22bfloat162_rn(make_float2(a, b));
  return u.i;
}

// ---------------- weight transpose via LDS tile (coalesced both ways) ------
// Wt[f][d] = bf16(W[d][f]); W is [D][256] fp32.
__global__ __launch_bounds__(256) void wtrans_kernel(
    const float* __restrict__ Wq, const float* __restrict__ Wk,
    const float* __restrict__ Wv, const float* __restrict__ Wfc,
    short* __restrict__ Wqt, short* __restrict__ Wkt,
    short* __restrict__ Wvt, short* __restrict__ Wfct) {
  int y = blockIdx.y;
  const float* W; short* Wt; int D;
  if (y == 0)      { W = Wq;  Wt = Wqt;  D = 512; }
  else if (y == 1) { W = Wk;  Wt = Wkt;  D = 512; }
  else if (y == 2) { W = Wv;  Wt = Wvt;  D = 512; }
  else             { W = Wfc; Wt = Wfct; D = 256; }
  int tiles_d = D >> 6;
  int bx = blockIdx.x;
  if (bx >= tiles_d * 4) return;
  int d0 = (bx % tiles_d) * 64, f0 = (bx / tiles_d) * 64;

  __shared__ short Ts[64][68];
  int t = threadIdx.x;
  int r = t >> 2, c16 = (t & 3) * 16;
  {
    const float* src = W + (size_t)(d0 + r) * F_ + f0 + c16;
    f32x4 v0 = *(const f32x4*)(src);
    f32x4 v1 = *(const f32x4*)(src + 4);
    f32x4 v2 = *(const f32x4*)(src + 8);
    f32x4 v3 = *(const f32x4*)(src + 12);
    s16x8 s0, s1;
    ((int*)&s0)[0] = pk2bf(v0[0], v0[1]); ((int*)&s0)[1] = pk2bf(v0[2], v0[3]);
    ((int*)&s0)[2] = pk2bf(v1[0], v1[1]); ((int*)&s0)[3] = pk2bf(v1[2], v1[3]);
    ((int*)&s1)[0] = pk2bf(v2[0], v2[1]); ((int*)&s1)[1] = pk2bf(v2[2], v2[3]);
    ((int*)&s1)[2] = pk2bf(v3[0], v3[1]); ((int*)&s1)[3] = pk2bf(v3[2], v3[3]);
    *(s16x8*)(&Ts[r][c16]) = s0;
    *(s16x8*)(&Ts[r][c16 + 8]) = s1;
  }
  __syncthreads();
  {
    int fr = t >> 2, dc16 = (t & 3) * 16;
    s16x8 o0, o1;
    for (int j = 0; j < 8; ++j) o0[j] = Ts[dc16 + j][fr];
    for (int j = 0; j < 8; ++j) o1[j] = Ts[dc16 + 8 + j][fr];
    short* dst = Wt + (size_t)(f0 + fr) * D + d0 + dc16;
    *(s16x8*)dst = o0;
    *(s16x8*)(dst + 8) = o1;
  }
}

// ---------------- QKV projection: 64 rows x 256 cols (full N), BK=64 ------
// 512 threads, register prefetch pipeline. (unchanged from round 6 — passed)
__global__ __launch_bounds__(512, 2) void proj_kernel(
    const float* __restrict__ feat1, const float* __restrict__ feat2,
    const short* __restrict__ Wqt, const short* __restrict__ Wkt,
    const short* __restrict__ Wvt,
    const float* __restrict__ bq, const float* __restrict__ bk,
    const float* __restrict__ bv,
    short* __restrict__ Qw, short* __restrict__ Kw, short* __restrict__ Vtw) {
  const float* A; const short* Wt; const float* bias; short* outp;
  float scale; int trans;
  if (blockIdx.y == 0)      { A = feat1; Wt = Wqt; bias = bq; outp = Qw;  scale = 0.0625f; trans = 0; }
  else if (blockIdx.y == 1) { A = feat2; Wt = Wkt; bias = bk; outp = Kw;  scale = 1.0f;    trans = 0; }
  else                      { A = feat2; Wt = Wvt; bias = bv; outp = Vtw; scale = 1.0f;    trans = 1; }

  __shared__ __align__(16) short As[64][72];
  __shared__ __align__(16) short Ws2[256][72];

  int m0 = blockIdx.x * 64;
  int t = threadIdx.x;
  int w = t >> 6, L = t & 63, rowA = L & 15, quad = L >> 4;
  int wy = w & 1, wx = w >> 1;

  int ar = t >> 3, ac8 = (t & 7) * 8;
  int wr = t >> 1, wc32 = (t & 1) * 32;

  f32x4 av0, av1;
  s16x8 wv[4];
  {
    const float* asrc = A + (size_t)(m0 + ar) * D_ + ac8;
    av0 = *(const f32x4*)(asrc);
    av1 = *(const f32x4*)(asrc + 4);
    const short* wsrc = Wt + (size_t)wr * D_ + wc32;
    for (int j = 0; j < 4; ++j) wv[j] = *(const s16x8*)(wsrc + j * 8);
  }

  f32x4 acc[2][4];
  for (int i = 0; i < 2; ++i)
    for (int j = 0; j < 4; ++j) acc[i][j] = (f32x4){0.f, 0.f, 0.f, 0.f};

  for (int k0 = 0; k0 < D_; k0 += 64) {
    {
      s16x8 s;
      ((int*)&s)[0] = pk2bf(av0[0], av0[1]); ((int*)&s)[1] = pk2bf(av0[2], av0[3]);
      ((int*)&s)[2] = pk2bf(av1[0], av1[1]); ((int*)&s)[3] = pk2bf(av1[2], av1[3]);
      *(s16x8*)(&As[ar][ac8]) = s;
      for (int j = 0; j < 4; ++j) *(s16x8*)(&Ws2[wr][wc32 + j * 8]) = wv[j];
    }
    __syncthreads();
    if (k0 + 64 < D_) {
      const float* asrc = A + (size_t)(m0 + ar) * D_ + k0 + 64 + ac8;
      av0 = *(const f32x4*)(asrc);
      av1 = *(const f32x4*)(asrc + 4);
      const short* wsrc = Wt + (size_t)wr * D_ + k0 + 64 + wc32;
      for (int j = 0; j < 4; ++j) wv[j] = *(const s16x8*)(wsrc + j * 8);
    }
    for (int kt = 0; kt < 2; ++kt) {
      s16x8 a[2];
      for (int mt = 0; mt < 2; ++mt)
        a[mt] = *(const s16x8*)(&As[wy * 32 + mt * 16 + rowA][kt * 32 + quad * 8]);
      for (int nt = 0; nt < 4; ++nt) {
        s16x8 bfr = *(const s16x8*)(&Ws2[wx * 64 + nt * 16 + rowA][kt * 32 + quad * 8]);
        for (int mt = 0; mt < 2; ++mt)
          acc[mt][nt] = __builtin_amdgcn_mfma_f32_16x16x32_bf16(a[mt], bfr, acc[mt][nt], 0, 0, 0);
      }
    }
    __syncthreads();
  }

  if (!trans) {
    float bn[4];
    for (int nt = 0; nt < 4; ++nt) bn[nt] = bias[wx * 64 + nt * 16 + rowA];
    for (int mt = 0; mt < 2; ++mt) {
      int m = m0 + wy * 32 + mt * 16 + quad * 4;
      for (int nt = 0; nt < 4; ++nt) {
        int n = wx * 64 + nt * 16 + rowA;
        for (int r = 0; r < 4; ++r)
          outp[(size_t)(m + r) * F_ + n] = f2bf((acc[mt][nt][r] + bn[nt]) * scale);
      }
    }
  } else {
    int bb = m0 >> 11;
    int tbase = m0 & (S2_ - 1);
    float bn[4];
    for (int nt = 0; nt < 4; ++nt) bn[nt] = bias[wx * 64 + nt * 16 + rowA];
    for (int nt = 0; nt < 4; ++nt) {
      int f = wx * 64 + nt * 16 + rowA;
      for (int mt = 0; mt < 2; ++mt) {
        int tt = tbase + wy * 32 + mt * 16 + quad * 4;
        s16x4 o;
        for (int r = 0; r < 4; ++r) o[r] = f2bf(acc[mt][nt][r] + bn[nt]);
        *(s16x4*)(outp + ((size_t)bb * F_ + f) * S2_ + tt) = o;
      }
    }
  }
}

// ---------------- flash attention + fused FC ------------------------------
// Main loop unchanged (round-5 wave-specialized pipeline, 1 barrier/iter).
// NEW epilogue: 2 k-slabs of 128 / 4 barriers total (was 10). Slab-0 of Wfc
// is staged by the idle S-waves concurrently with PV's O-normalize.
__global__ __launch_bounds__(512, 2) void flash_kernel(
    const short* __restrict__ Q,    // [B][S1][F] bf16 (pre-scaled by 1/16)
    const short* __restrict__ K,    // [B][S2][F] bf16
    const short* __restrict__ Vt,   // [B][F][S2] bf16
    const short* __restrict__ Wfct, // [256 g][256 k] bf16
    const float* __restrict__ bfc,  // [256] fp32
    float* __restrict__ out) {      // [B][S1][F] fp32
  __shared__ __align__(16) short Ks[2][64][264];   // 67584 B
  __shared__ __align__(16) short Vs[2][256][72];   // 73728 B
  __shared__ __align__(16) short Ps[2][64][72];    // 18432 B  (sum 159744)

  int b = blockIdx.x >> 5;
  int s0 = (blockIdx.x & 31) * 64;
  int t = threadIdx.x;
  int w = t >> 6, L = t & 63, rowA = L & 15, quad = L >> 4;
  int isS = (w < 4);

  const short* Kb = K + (size_t)b * S2_ * F_;
  const short* Vb = Vt + (size_t)b * F_ * S2_;

  int kr = t >> 5, kc8 = (t & 31) * 8;
  int vr = t >> 3, vc8 = (t & 7) * 8;

  int rs = (w & 1) * 32, cs = ((w >> 1) & 1) * 32;   // S-wave quadrant
  int mg = (w - 4) & 1, fg = ((w - 4) >> 1) & 1;     // PV-wave tile

  s16x8 qf[2][8];
  if (isS) {
    const short* Qb = Q + ((size_t)b * S1_ + s0 + rs) * F_;
    for (int mt = 0; mt < 2; ++mt)
      for (int kt = 0; kt < 8; ++kt)
        qf[mt][kt] = *(const s16x8*)(Qb + (size_t)(mt * 16 + rowA) * F_ + kt * 32 + quad * 8);
  }
  f32x4 o[2][8];
  for (int i = 0; i < 2; ++i)
    for (int j = 0; j < 8; ++j) o[i][j] = (f32x4){0.f, 0.f, 0.f, 0.f};
  float l_lane[2][4] = {{0.f,0.f,0.f,0.f},{0.f,0.f,0.f,0.f}};

  s16x8 kpre[4], vpre[4];
  for (int p = 0; p < 4; ++p)
    kpre[p] = *(const s16x8*)(Kb + (size_t)(kr + p * 16) * F_ + kc8);
  for (int p = 0; p < 4; ++p)
    *(s16x8*)(&Ks[0][kr + p * 16][kc8]) = kpre[p];
  for (int p = 0; p < 4; ++p)
    kpre[p] = *(const s16x8*)(Kb + (size_t)(64 + kr + p * 16) * F_ + kc8);
  for (int p = 0; p < 4; ++p)
    vpre[p] = *(const s16x8*)(Vb + (size_t)(vr + p * 64) * S2_ + vc8);

  for (int it = 0; it <= 32; ++it) {
    int cb = it & 1;
    __syncthreads();
    if (it < 32) {
      for (int p = 0; p < 4; ++p)
        *(s16x8*)(&Vs[cb][vr + p * 64][vc8]) = vpre[p];
      if (it < 31) {
        for (int p = 0; p < 4; ++p)
          *(s16x8*)(&Ks[1 - cb][kr + p * 16][kc8]) = kpre[p];
        int n0 = (it + 1) * 64;
        for (int p = 0; p < 4; ++p)
          vpre[p] = *(const s16x8*)(Vb + (size_t)(vr + p * 64) * S2_ + n0 + vc8);
      }
      if (it < 30) {
        int n0 = (it + 2) * 64;
        for (int p = 0; p < 4; ++p)
          kpre[p] = *(const s16x8*)(Kb + (size_t)(n0 + kr + p * 16) * F_ + kc8);
      }
    }
    if (isS) {
      if (it < 32) {
        f32x4 s[2][2];
        for (int i = 0; i < 2; ++i)
          for (int j = 0; j < 2; ++j) s[i][j] = (f32x4){0.f, 0.f, 0.f, 0.f};
        for (int kt = 0; kt < 8; ++kt) {
          s16x8 bf0 = *(const s16x8*)(&Ks[cb][cs + rowA][kt * 32 + quad * 8]);
          s16x8 bf1 = *(const s16x8*)(&Ks[cb][cs + 16 + rowA][kt * 32 + quad * 8]);
          for (int mt = 0; mt < 2; ++mt) {
            s[mt][0] = __builtin_amdgcn_mfma_f32_16x16x32_bf16(qf[mt][kt], bf0, s[mt][0], 0, 0, 0);
            s[mt][1] = __builtin_amdgcn_mfma_f32_16x16x32_bf16(qf[mt][kt], bf1, s[mt][1], 0, 0, 0);
          }
        }
        for (int mt = 0; mt < 2; ++mt)
          for (int nt = 0; nt < 2; ++nt)
            for (int r = 0; r < 4; ++r) {
              float p = __expf(s[mt][nt][r]);
              l_lane[mt][r] += p;
              Ps[cb][rs + mt * 16 + quad * 4 + r][cs + nt * 16 + rowA] = f2bf(p);
            }
      }
    } else {
      if (it > 0) {
        int pb = 1 - cb;
        s16x8 pa[2][2];
        for (int mt = 0; mt < 2; ++mt)
          for (int kt = 0; kt < 2; ++kt)
            pa[mt][kt] = *(const s16x8*)(&Ps[pb][mg * 32 + mt * 16 + rowA][kt * 32 + quad * 8]);
        for (int ft = 0; ft < 8; ++ft)
          for (int kt = 0; kt < 2; ++kt) {
            s16x8 vf = *(const s16x8*)(&Vs[pb][fg * 128 + ft * 16 + rowA][kt * 32 + quad * 8]);
            for (int mt = 0; mt < 2; ++mt)
              o[mt][ft] = __builtin_amdgcn_mfma_f32_16x16x32_bf16(pa[mt][kt], vf, o[mt][ft], 0, 0, 0);
          }
      }
    }
  }

  // ---- epilogue: 4 barriers total ----
  float* lf = (float*)&Ps[0][0][0];               // [2 col-halves][64 rows]
  short (*Os)[264] = (short(*)[264])&Ks[0][0][0]; // 64 x 264 bf16 O (33.8 KB)
  short (*Wg)[132] = (short(*)[132])&Vs[0][0][0]; // 256 g x 132 (67.6 KB)

  if (isS) {
    for (int mt = 0; mt < 2; ++mt)
      for (int r = 0; r < 4; ++r) {
        float x = l_lane[mt][r];
        for (int off = 1; off < 16; off <<= 1)
          x += __shfl_xor(x, off, 64);
        if (rowA == 0)
          lf[((w >> 1) & 1) * 64 + rs + mt * 16 + quad * 4 + r] = x;
      }
  }
  __syncthreads();   // sync1: lf ready, Vs dead
  if (!isS) {        // PV-waves: normalize O -> bf16 Os
    for (int mt = 0; mt < 2; ++mt)
      for (int r = 0; r < 4; ++r) {
        int row = mg * 32 + mt * 16 + quad * 4 + r;
        float inv = 1.0f / (lf[row] + lf[64 + row]);
        for (int ft = 0; ft < 8; ++ft)
          Os[row][fg * 128 + ft * 16 + rowA] = f2bf(o[mt][ft][r] * inv);
      }
  } else {           // S-waves (idle): stage Wfc slab0 (k 0..127), 1 row/thread
    const short* src = Wfct + (size_t)t * F_;
    for (int j = 0; j < 16; ++j)
      *(s16x8*)(&Wg[t][j * 8]) = *(const s16x8*)(src + j * 8);
  }
  __syncthreads();   // sync2: Os + slab0 ready

  int fr = w & 3, gh = w >> 2;
  s16x8 af[8];
  for (int kt = 0; kt < 8; ++kt)
    af[kt] = *(const s16x8*)(&Os[fr * 16 + rowA][kt * 32 + quad * 8]);
  f32x4 acc[8];
  for (int i = 0; i < 8; ++i) acc[i] = (f32x4){0.f, 0.f, 0.f, 0.f};

  for (int nt = 0; nt < 8; ++nt) {
    int g = gh * 128 + nt * 16 + rowA;
    for (int kt = 0; kt < 4; ++kt) {
      s16x8 bfr = *(const s16x8*)(&Wg[g][kt * 32 + quad * 8]);
      acc[nt] = __builtin_amdgcn_mfma_f32_16x16x32_bf16(af[kt], bfr, acc[nt], 0, 0, 0);
    }
  }
  __syncthreads();   // sync3: slab0 consumed
  {                  // stage slab1 (k 128..255), all 512 threads
    int r2 = t >> 1, c2 = (t & 1) * 64;
    const short* src = Wfct + (size_t)r2 * F_ + 128 + c2;
    for (int j = 0; j < 8; ++j)
      *(s16x8*)(&Wg[r2][c2 + j * 8]) = *(const s16x8*)(src + j * 8);
  }
  __syncthreads();   // sync4: slab1 ready
  for (int nt = 0; nt < 8; ++nt) {
    int g = gh * 128 + nt * 16 + rowA;
    for (int kt = 0; kt < 4; ++kt) {
      s16x8 bfr = *(const s16x8*)(&Wg[g][kt * 32 + quad * 8]);
      acc[nt] = __builtin_amdgcn_mfma_f32_16x16x32_bf16(af[4 + kt], bfr, acc[nt], 0, 0, 0);
    }
  }

  float bn[8];
  for (int nt = 0; nt < 8; ++nt) bn[nt] = bfc[gh * 128 + nt * 16 + rowA];
  float* Ob = out + ((size_t)b * S1_ + s0 + fr * 16) * F_;
  for (int nt = 0; nt < 8; ++nt) {
    int g = gh * 128 + nt * 16 + rowA;
    for (int r = 0; r < 4; ++r)
      Ob[(size_t)(quad * 4 + r) * F_ + g] = acc[nt][r] + bn[nt];
  }
}

extern "C" void kernel_launch(void* const* d_in, const int* in_sizes, int n_in,
                              void* d_out, int out_size, void* d_ws, size_t ws_size,
                              hipStream_t stream) {
  const float* feat1 = (const float*)d_in[0];
  const float* feat2 = (const float*)d_in[1];
  const float* Wq  = (const float*)d_in[2];
  const float* bq  = (const float*)d_in[3];
  const float* Wk  = (const float*)d_in[4];
  const float* bk  = (const float*)d_in[5];
  const float* Wv  = (const float*)d_in[6];
  const float* bv  = (const float*)d_in[7];
  const float* Wfc = (const float*)d_in[8];
  const float* bfc = (const float*)d_in[9];
  float* out = (float*)d_out;
  char* ws = (char*)d_ws;

  // workspace layout: within the proven-safe 33 MB footprint
  short* Qw   = (short*)(ws);                       // 8 MB  [B][S1][F]
  short* Kw   = (short*)(ws + (size_t)(8u  << 20)); // 8 MB  [B][S2][F]
  short* Vtw  = (short*)(ws + (size_t)(16u << 20)); // 8 MB  [B][F][S2]
  short* Wqt  = (short*)(ws + (size_t)(32u << 20)); // 256KB [F][D]
  short* Wkt  = Wqt + 256 * 512;
  short* Wvt  = Wkt + 256 * 512;
  short* Wfct = Wvt + 256 * 512;                    // [256][256]

  wtrans_kernel<<<dim3(32, 4), 256, 0, stream>>>(Wq, Wk, Wv, Wfc, Wqt, Wkt, Wvt, Wfct);
  proj_kernel<<<dim3(256, 3), 512, 0, stream>>>(feat1, feat2, Wqt, Wkt, Wvt,
                                                bq, bk, bv, Qw, Kw, Vtw);
  flash_kernel<<<dim3(256), 512, 0, stream>>>(Qw, Kw, Vtw, Wfct, bfc, out);
}

// Round 8
// 205.843 us; speedup vs baseline: 1.0195x; 1.0195x over previous
//
#include <hip/hip_runtime.h>
#include <hip/hip_bf16.h>

#define B_ 8
#define S1_ 2048
#define S2_ 2048
#define D_ 512
#define F_ 256

typedef __attribute__((ext_vector_type(4))) float f32x4;
typedef __attribute__((ext_vector_type(8))) short s16x8;
typedef __attribute__((ext_vector_type(4))) short s16x4;

__device__ __forceinline__ short f2bf(float x) {
  union { float f; unsigned u; } v; v.f = x;
  unsigned r = v.u + 0x7fffu + ((v.u >> 16) & 1u);
  return (short)(r >> 16);
}

__device__ __forceinline__ int pk2bf(float a, float b) {
  union { __hip_bfloat162 h; int i; } u;
  u.h = __float22bfloat162_rn(make_float2(a, b));
  return u.i;
}

// ---------------- weight transpose via LDS tile (coalesced both ways) ------
__global__ __launch_bounds__(256) void wtrans_kernel(
    const float* __restrict__ Wq, const float* __restrict__ Wk,
    const float* __restrict__ Wv, const float* __restrict__ Wfc,
    short* __restrict__ Wqt, short* __restrict__ Wkt,
    short* __restrict__ Wvt, short* __restrict__ Wfct) {
  int y = blockIdx.y;
  const float* W; short* Wt; int D;
  if (y == 0)      { W = Wq;  Wt = Wqt;  D = 512; }
  else if (y == 1) { W = Wk;  Wt = Wkt;  D = 512; }
  else if (y == 2) { W = Wv;  Wt = Wvt;  D = 512; }
  else             { W = Wfc; Wt = Wfct; D = 256; }
  int tiles_d = D >> 6;
  int bx = blockIdx.x;
  if (bx >= tiles_d * 4) return;
  int d0 = (bx % tiles_d) * 64, f0 = (bx / tiles_d) * 64;

  __shared__ short Ts[64][68];
  int t = threadIdx.x;
  int r = t >> 2, c16 = (t & 3) * 16;
  {
    const float* src = W + (size_t)(d0 + r) * F_ + f0 + c16;
    f32x4 v0 = *(const f32x4*)(src);
    f32x4 v1 = *(const f32x4*)(src + 4);
    f32x4 v2 = *(const f32x4*)(src + 8);
    f32x4 v3 = *(const f32x4*)(src + 12);
    s16x8 s0, s1;
    ((int*)&s0)[0] = pk2bf(v0[0], v0[1]); ((int*)&s0)[1] = pk2bf(v0[2], v0[3]);
    ((int*)&s0)[2] = pk2bf(v1[0], v1[1]); ((int*)&s0)[3] = pk2bf(v1[2], v1[3]);
    ((int*)&s1)[0] = pk2bf(v2[0], v2[1]); ((int*)&s1)[1] = pk2bf(v2[2], v2[3]);
    ((int*)&s1)[2] = pk2bf(v3[0], v3[1]); ((int*)&s1)[3] = pk2bf(v3[2], v3[3]);
    *(s16x8*)(&Ts[r][c16]) = s0;
    *(s16x8*)(&Ts[r][c16 + 8]) = s1;
  }
  __syncthreads();
  {
    int fr = t >> 2, dc16 = (t & 3) * 16;
    s16x8 o0, o1;
    for (int j = 0; j < 8; ++j) o0[j] = Ts[dc16 + j][fr];
    for (int j = 0; j < 8; ++j) o1[j] = Ts[dc16 + 8 + j][fr];
    short* dst = Wt + (size_t)(f0 + fr) * D + d0 + dc16;
    *(s16x8*)dst = o0;
    *(s16x8*)(dst + 8) = o1;
  }
}

// ---------------- QKV projection: 64 rows x 256 cols (full N), BK=64 ------
// 512 threads, register prefetch pipeline. (unchanged — proven R6/R7)
__global__ __launch_bounds__(512, 2) void proj_kernel(
    const float* __restrict__ feat1, const float* __restrict__ feat2,
    const short* __restrict__ Wqt, const short* __restrict__ Wkt,
    const short* __restrict__ Wvt,
    const float* __restrict__ bq, const float* __restrict__ bk,
    const float* __restrict__ bv,
    short* __restrict__ Qw, short* __restrict__ Kw, short* __restrict__ Vtw) {
  const float* A; const short* Wt; const float* bias; short* outp;
  float scale; int trans;
  if (blockIdx.y == 0)      { A = feat1; Wt = Wqt; bias = bq; outp = Qw;  scale = 0.0625f; trans = 0; }
  else if (blockIdx.y == 1) { A = feat2; Wt = Wkt; bias = bk; outp = Kw;  scale = 1.0f;    trans = 0; }
  else                      { A = feat2; Wt = Wvt; bias = bv; outp = Vtw; scale = 1.0f;    trans = 1; }

  __shared__ __align__(16) short As[64][72];
  __shared__ __align__(16) short Ws2[256][72];

  int m0 = blockIdx.x * 64;
  int t = threadIdx.x;
  int w = t >> 6, L = t & 63, rowA = L & 15, quad = L >> 4;
  int wy = w & 1, wx = w >> 1;

  int ar = t >> 3, ac8 = (t & 7) * 8;
  int wr = t >> 1, wc32 = (t & 1) * 32;

  f32x4 av0, av1;
  s16x8 wv[4];
  {
    const float* asrc = A + (size_t)(m0 + ar) * D_ + ac8;
    av0 = *(const f32x4*)(asrc);
    av1 = *(const f32x4*)(asrc + 4);
    const short* wsrc = Wt + (size_t)wr * D_ + wc32;
    for (int j = 0; j < 4; ++j) wv[j] = *(const s16x8*)(wsrc + j * 8);
  }

  f32x4 acc[2][4];
  for (int i = 0; i < 2; ++i)
    for (int j = 0; j < 4; ++j) acc[i][j] = (f32x4){0.f, 0.f, 0.f, 0.f};

  for (int k0 = 0; k0 < D_; k0 += 64) {
    {
      s16x8 s;
      ((int*)&s)[0] = pk2bf(av0[0], av0[1]); ((int*)&s)[1] = pk2bf(av0[2], av0[3]);
      ((int*)&s)[2] = pk2bf(av1[0], av1[1]); ((int*)&s)[3] = pk2bf(av1[2], av1[3]);
      *(s16x8*)(&As[ar][ac8]) = s;
      for (int j = 0; j < 4; ++j) *(s16x8*)(&Ws2[wr][wc32 + j * 8]) = wv[j];
    }
    __syncthreads();
    if (k0 + 64 < D_) {
      const float* asrc = A + (size_t)(m0 + ar) * D_ + k0 + 64 + ac8;
      av0 = *(const f32x4*)(asrc);
      av1 = *(const f32x4*)(asrc + 4);
      const short* wsrc = Wt + (size_t)wr * D_ + k0 + 64 + wc32;
      for (int j = 0; j < 4; ++j) wv[j] = *(const s16x8*)(wsrc + j * 8);
    }
    for (int kt = 0; kt < 2; ++kt) {
      s16x8 a[2];
      for (int mt = 0; mt < 2; ++mt)
        a[mt] = *(const s16x8*)(&As[wy * 32 + mt * 16 + rowA][kt * 32 + quad * 8]);
      for (int nt = 0; nt < 4; ++nt) {
        s16x8 bfr = *(const s16x8*)(&Ws2[wx * 64 + nt * 16 + rowA][kt * 32 + quad * 8]);
        for (int mt = 0; mt < 2; ++mt)
          acc[mt][nt] = __builtin_amdgcn_mfma_f32_16x16x32_bf16(a[mt], bfr, acc[mt][nt], 0, 0, 0);
      }
    }
    __syncthreads();
  }

  if (!trans) {
    float bn[4];
    for (int nt = 0; nt < 4; ++nt) bn[nt] = bias[wx * 64 + nt * 16 + rowA];
    for (int mt = 0; mt < 2; ++mt) {
      int m = m0 + wy * 32 + mt * 16 + quad * 4;
      for (int nt = 0; nt < 4; ++nt) {
        int n = wx * 64 + nt * 16 + rowA;
        for (int r = 0; r < 4; ++r)
          outp[(size_t)(m + r) * F_ + n] = f2bf((acc[mt][nt][r] + bn[nt]) * scale);
      }
    }
  } else {
    int bb = m0 >> 11;
    int tbase = m0 & (S2_ - 1);
    float bn[4];
    for (int nt = 0; nt < 4; ++nt) bn[nt] = bias[wx * 64 + nt * 16 + rowA];
    for (int nt = 0; nt < 4; ++nt) {
      int f = wx * 64 + nt * 16 + rowA;
      for (int mt = 0; mt < 2; ++mt) {
        int tt = tbase + wy * 32 + mt * 16 + quad * 4;
        s16x4 o;
        for (int r = 0; r < 4; ++r) o[r] = f2bf(acc[mt][nt][r] + bn[nt]);
        *(s16x4*)(outp + ((size_t)bb * F_ + f) * S2_ + tt) = o;
      }
    }
  }
}

// ---------------- flash attention: wave-specialized pipeline --------------
// EXACT round-5 body (proven 58.8 us) + XCD-aware block swizzle:
// b = blockIdx.x & 7 so all 32 q-tiles of a batch land on one XCD and its
// K/V (2 MB) stays resident in that XCD's 4 MB L2.
__global__ __launch_bounds__(512, 2) void flash_kernel(
    const short* __restrict__ Q,    // [B][S1][F] bf16 (scaled)
    const short* __restrict__ K,    // [B][S2][F] bf16
    const short* __restrict__ Vt,   // [B][F][S2] bf16
    short* __restrict__ O) {        // [B][S1][F] bf16 (normalized)
  __shared__ __align__(16) short Ks[2][64][264];   // 67584 B
  __shared__ __align__(16) short Vs[2][256][72];   // 73728 B
  __shared__ __align__(16) short Ps[2][64][72];    // 18432 B  (sum 159744)

  int b = blockIdx.x & 7;            // XCD-aware: batch = block % 8
  int s0 = (blockIdx.x >> 3) * 64;
  int t = threadIdx.x;
  int w = t >> 6, L = t & 63, rowA = L & 15, quad = L >> 4;
  int isS = (w < 4);

  const short* Kb = K + (size_t)b * S2_ * F_;
  const short* Vb = Vt + (size_t)b * F_ * S2_;

  int kr = t >> 5, kc8 = (t & 31) * 8;
  int vr = t >> 3, vc8 = (t & 7) * 8;

  int rs = (w & 1) * 32, cs = ((w >> 1) & 1) * 32;   // S-wave quadrant
  int mg = (w - 4) & 1, fg = ((w - 4) >> 1) & 1;     // PV-wave tile

  s16x8 qf[2][8];
  if (isS) {
    const short* Qb = Q + ((size_t)b * S1_ + s0 + rs) * F_;
    for (int mt = 0; mt < 2; ++mt)
      for (int kt = 0; kt < 8; ++kt)
        qf[mt][kt] = *(const s16x8*)(Qb + (size_t)(mt * 16 + rowA) * F_ + kt * 32 + quad * 8);
  }
  f32x4 o[2][8];
  for (int i = 0; i < 2; ++i)
    for (int j = 0; j < 8; ++j) o[i][j] = (f32x4){0.f, 0.f, 0.f, 0.f};
  float l_lane[2][4] = {{0.f,0.f,0.f,0.f},{0.f,0.f,0.f,0.f}};

  s16x8 kpre[4], vpre[4];
  for (int p = 0; p < 4; ++p)
    kpre[p] = *(const s16x8*)(Kb + (size_t)(kr + p * 16) * F_ + kc8);
  for (int p = 0; p < 4; ++p)
    *(s16x8*)(&Ks[0][kr + p * 16][kc8]) = kpre[p];
  for (int p = 0; p < 4; ++p)
    kpre[p] = *(const s16x8*)(Kb + (size_t)(64 + kr + p * 16) * F_ + kc8);
  for (int p = 0; p < 4; ++p)
    vpre[p] = *(const s16x8*)(Vb + (size_t)(vr + p * 64) * S2_ + vc8);

  for (int it = 0; it <= 32; ++it) {
    int cb = it & 1;
    __syncthreads();
    if (it < 32) {
      for (int p = 0; p < 4; ++p)
        *(s16x8*)(&Vs[cb][vr + p * 64][vc8]) = vpre[p];
      if (it < 31) {
        for (int p = 0; p < 4; ++p)
          *(s16x8*)(&Ks[1 - cb][kr + p * 16][kc8]) = kpre[p];
        int n0 = (it + 1) * 64;
        for (int p = 0; p < 4; ++p)
          vpre[p] = *(const s16x8*)(Vb + (size_t)(vr + p * 64) * S2_ + n0 + vc8);
      }
      if (it < 30) {
        int n0 = (it + 2) * 64;
        for (int p = 0; p < 4; ++p)
          kpre[p] = *(const s16x8*)(Kb + (size_t)(n0 + kr + p * 16) * F_ + kc8);
      }
    }
    if (isS) {
      if (it < 32) {
        f32x4 s[2][2];
        for (int i = 0; i < 2; ++i)
          for (int j = 0; j < 2; ++j) s[i][j] = (f32x4){0.f, 0.f, 0.f, 0.f};
        for (int kt = 0; kt < 8; ++kt) {
          s16x8 bf0 = *(const s16x8*)(&Ks[cb][cs + rowA][kt * 32 + quad * 8]);
          s16x8 bf1 = *(const s16x8*)(&Ks[cb][cs + 16 + rowA][kt * 32 + quad * 8]);
          for (int mt = 0; mt < 2; ++mt) {
            s[mt][0] = __builtin_amdgcn_mfma_f32_16x16x32_bf16(qf[mt][kt], bf0, s[mt][0], 0, 0, 0);
            s[mt][1] = __builtin_amdgcn_mfma_f32_16x16x32_bf16(qf[mt][kt], bf1, s[mt][1], 0, 0, 0);
          }
        }
        for (int mt = 0; mt < 2; ++mt)
          for (int nt = 0; nt < 2; ++nt)
            for (int r = 0; r < 4; ++r) {
              float p = __expf(s[mt][nt][r]);
              l_lane[mt][r] += p;
              Ps[cb][rs + mt * 16 + quad * 4 + r][cs + nt * 16 + rowA] = f2bf(p);
            }
      }
    } else {
      if (it > 0) {
        int pb = 1 - cb;
        s16x8 pa[2][2];
        for (int mt = 0; mt < 2; ++mt)
          for (int kt = 0; kt < 2; ++kt)
            pa[mt][kt] = *(const s16x8*)(&Ps[pb][mg * 32 + mt * 16 + rowA][kt * 32 + quad * 8]);
        for (int ft = 0; ft < 8; ++ft)
          for (int kt = 0; kt < 2; ++kt) {
            s16x8 vf = *(const s16x8*)(&Vs[pb][fg * 128 + ft * 16 + rowA][kt * 32 + quad * 8]);
            for (int mt = 0; mt < 2; ++mt)
              o[mt][ft] = __builtin_amdgcn_mfma_f32_16x16x32_bf16(pa[mt][kt], vf, o[mt][ft], 0, 0, 0);
          }
      }
    }
  }

  // l totals: S-waves reduce and publish to LDS (overlay on dead Ks)
  float* lf = (float*)&Ks[0][0][0];   // [2 col-halves][64 rows]
  if (isS) {
    for (int mt = 0; mt < 2; ++mt)
      for (int r = 0; r < 4; ++r) {
        float x = l_lane[mt][r];
        for (int off = 1; off < 16; off <<= 1)
          x += __shfl_xor(x, off, 64);
        if (rowA == 0)
          lf[((w >> 1) & 1) * 64 + rs + mt * 16 + quad * 4 + r] = x;
      }
  }
  __syncthreads();
  if (!isS) {
    short* Ob = O + ((size_t)b * S1_ + s0) * F_;
    for (int mt = 0; mt < 2; ++mt)
      for (int r = 0; r < 4; ++r) {
        int row = mg * 32 + mt * 16 + quad * 4 + r;
        float inv = 1.0f / (lf[row] + lf[64 + row]);
        for (int ft = 0; ft < 8; ++ft)
          Ob[(size_t)row * F_ + fg * 128 + ft * 16 + rowA] = f2bf(o[mt][ft][r] * inv);
      }
  }
}

// ---------------- FC: 128x128 tile, BK=64, fp32 out (proven R5) -----------
__global__ __launch_bounds__(256) void fc_kernel(
    const short* __restrict__ AO,   // [16384][256] bf16
    const short* __restrict__ Wt,   // [256][256] bf16, Wt[g][f]
    const float* __restrict__ bias,
    float* __restrict__ out) {
  __shared__ __align__(16) short As[128][72];
  __shared__ __align__(16) short Ws[128][72];

  int m0 = blockIdx.x * 128;
  int n0 = blockIdx.y * 128;
  int t = threadIdx.x;
  int w = t >> 6, L = t & 63, rowA = L & 15, quad = L >> 4;
  int wy = w >> 1, wx = w & 1;
  int srow = t >> 3, sc8 = (t & 7) * 8;

  f32x4 acc[4][4];
  for (int i = 0; i < 4; ++i)
    for (int j = 0; j < 4; ++j) acc[i][j] = (f32x4){0.f, 0.f, 0.f, 0.f};

  for (int k0 = 0; k0 < F_; k0 += 64) {
    for (int p = 0; p < 4; ++p) {
      int r = p * 32 + srow;
      *(s16x8*)(&As[r][sc8]) = *(const s16x8*)(AO + (size_t)(m0 + r) * F_ + k0 + sc8);
      *(s16x8*)(&Ws[r][sc8]) = *(const s16x8*)(Wt + (size_t)(n0 + r) * F_ + k0 + sc8);
    }
    __syncthreads();
    for (int kt = 0; kt < 2; ++kt) {
      s16x8 a[4];
      for (int mt = 0; mt < 4; ++mt)
        a[mt] = *(const s16x8*)(&As[wy * 64 + mt * 16 + rowA][kt * 32 + quad * 8]);
      for (int nt = 0; nt < 4; ++nt) {
        s16x8 bfr = *(const s16x8*)(&Ws[wx * 64 + nt * 16 + rowA][kt * 32 + quad * 8]);
        for (int mt = 0; mt < 4; ++mt)
          acc[mt][nt] = __builtin_amdgcn_mfma_f32_16x16x32_bf16(a[mt], bfr, acc[mt][nt], 0, 0, 0);
      }
    }
    __syncthreads();
  }

  float bn[4];
  for (int nt = 0; nt < 4; ++nt) bn[nt] = bias[n0 + wx * 64 + nt * 16 + rowA];
  for (int mt = 0; mt < 4; ++mt) {
    int m = m0 + wy * 64 + mt * 16 + quad * 4;
    for (int nt = 0; nt < 4; ++nt) {
      int n = n0 + wx * 64 + nt * 16 + rowA;
      for (int r = 0; r < 4; ++r)
        out[(size_t)(m + r) * F_ + n] = acc[mt][nt][r] + bn[nt];
    }
  }
}

extern "C" void kernel_launch(void* const* d_in, const int* in_sizes, int n_in,
                              void* d_out, int out_size, void* d_ws, size_t ws_size,
                              hipStream_t stream) {
  const float* feat1 = (const float*)d_in[0];
  const float* feat2 = (const float*)d_in[1];
  const float* Wq  = (const float*)d_in[2];
  const float* bq  = (const float*)d_in[3];
  const float* Wk  = (const float*)d_in[4];
  const float* bk  = (const float*)d_in[5];
  const float* Wv  = (const float*)d_in[6];
  const float* bv  = (const float*)d_in[7];
  const float* Wfc = (const float*)d_in[8];
  const float* bfc = (const float*)d_in[9];
  float* out = (float*)d_out;
  char* ws = (char*)d_ws;

  // workspace layout: 32.75 MB total (proven-safe footprint)
  short* Qw   = (short*)(ws);                       // 8 MB  [B][S1][F]
  short* Kw   = (short*)(ws + (size_t)(8u  << 20)); // 8 MB  [B][S2][F]
  short* Vtw  = (short*)(ws + (size_t)(16u << 20)); // 8 MB  [B][F][S2]
  short* AOw  = (short*)(ws + (size_t)(24u << 20)); // 8 MB  [B][S1][F]
  short* Wqt  = (short*)(ws + (size_t)(32u << 20)); // 256KB [F][D]
  short* Wkt  = Wqt + 256 * 512;
  short* Wvt  = Wkt + 256 * 512;
  short* Wfct = Wvt + 256 * 512;                    // [256][256]

  wtrans_kernel<<<dim3(32, 4), 256, 0, stream>>>(Wq, Wk, Wv, Wfc, Wqt, Wkt, Wvt, Wfct);
  proj_kernel<<<dim3(256, 3), 512, 0, stream>>>(feat1, feat2, Wqt, Wkt, Wvt,
                                                bq, bk, bv, Qw, Kw, Vtw);
  flash_kernel<<<dim3(256), 512, 0, stream>>>(Qw, Kw, Vtw, AOw);
  fc_kernel<<<dim3(128, 2), 256, 0, stream>>>(AOw, Wfct, bfc, out);
}

// Round 9
// 190.730 us; speedup vs baseline: 1.1003x; 1.0792x over previous
//
#include <hip/hip_runtime.h>
#include <hip/hip_bf16.h>

#define B_ 8
#define S1_ 2048
#define S2_ 2048
#define D_ 512
#define F_ 256

typedef __attribute__((ext_vector_type(4))) float f32x4;
typedef __attribute__((ext_vector_type(8))) short s16x8;
typedef __attribute__((ext_vector_type(4))) short s16x4;

__device__ __forceinline__ short f2bf(float x) {
  union { float f; unsigned u; } v; v.f = x;
  unsigned r = v.u + 0x7fffu + ((v.u >> 16) & 1u);
  return (short)(r >> 16);
}

__device__ __forceinline__ int pk2bf(float a, float b) {
  union { __hip_bfloat162 h; int i; } u;
  u.h = __float22bfloat162_rn(make_float2(a, b));
  return u.i;
}

// ---------------- weight transpose via LDS tile (coalesced both ways) ------
__global__ __launch_bounds__(256) void wtrans_kernel(
    const float* __restrict__ Wq, const float* __restrict__ Wk,
    const float* __restrict__ Wv, const float* __restrict__ Wfc,
    short* __restrict__ Wqt, short* __restrict__ Wkt,
    short* __restrict__ Wvt, short* __restrict__ Wfct) {
  int y = blockIdx.y;
  const float* W; short* Wt; int D;
  if (y == 0)      { W = Wq;  Wt = Wqt;  D = 512; }
  else if (y == 1) { W = Wk;  Wt = Wkt;  D = 512; }
  else if (y == 2) { W = Wv;  Wt = Wvt;  D = 512; }
  else             { W = Wfc; Wt = Wfct; D = 256; }
  int tiles_d = D >> 6;
  int bx = blockIdx.x;
  if (bx >= tiles_d * 4) return;
  int d0 = (bx % tiles_d) * 64, f0 = (bx / tiles_d) * 64;

  __shared__ short Ts[64][68];
  int t = threadIdx.x;
  int r = t >> 2, c16 = (t & 3) * 16;
  {
    const float* src = W + (size_t)(d0 + r) * F_ + f0 + c16;
    f32x4 v0 = *(const f32x4*)(src);
    f32x4 v1 = *(const f32x4*)(src + 4);
    f32x4 v2 = *(const f32x4*)(src + 8);
    f32x4 v3 = *(const f32x4*)(src + 12);
    s16x8 s0, s1;
    ((int*)&s0)[0] = pk2bf(v0[0], v0[1]); ((int*)&s0)[1] = pk2bf(v0[2], v0[3]);
    ((int*)&s0)[2] = pk2bf(v1[0], v1[1]); ((int*)&s0)[3] = pk2bf(v1[2], v1[3]);
    ((int*)&s1)[0] = pk2bf(v2[0], v2[1]); ((int*)&s1)[1] = pk2bf(v2[2], v2[3]);
    ((int*)&s1)[2] = pk2bf(v3[0], v3[1]); ((int*)&s1)[3] = pk2bf(v3[2], v3[3]);
    *(s16x8*)(&Ts[r][c16]) = s0;
    *(s16x8*)(&Ts[r][c16 + 8]) = s1;
  }
  __syncthreads();
  {
    int fr = t >> 2, dc16 = (t & 3) * 16;
    s16x8 o0, o1;
    for (int j = 0; j < 8; ++j) o0[j] = Ts[dc16 + j][fr];
    for (int j = 0; j < 8; ++j) o1[j] = Ts[dc16 + 8 + j][fr];
    short* dst = Wt + (size_t)(f0 + fr) * D + d0 + dc16;
    *(s16x8*)dst = o0;
    *(s16x8*)(dst + 8) = o1;
  }
}

// ---------------- QKV projection: 64 rows x 256 cols (full N), BK=64 ------
// R5 version verbatim: 256 threads, 3 blocks/CU. Proven fastest proj combo.
__global__ __launch_bounds__(256, 3) void proj_kernel(
    const float* __restrict__ feat1, const float* __restrict__ feat2,
    const short* __restrict__ Wqt, const short* __restrict__ Wkt,
    const short* __restrict__ Wvt,
    const float* __restrict__ bq, const float* __restrict__ bk,
    const float* __restrict__ bv,
    short* __restrict__ Qw, short* __restrict__ Kw, short* __restrict__ Vtw) {
  const float* A; const short* Wt; const float* bias; short* outp;
  float scale; int trans;
  if (blockIdx.y == 0)      { A = feat1; Wt = Wqt; bias = bq; outp = Qw;  scale = 0.0625f; trans = 0; }
  else if (blockIdx.y == 1) { A = feat2; Wt = Wkt; bias = bk; outp = Kw;  scale = 1.0f;    trans = 0; }
  else                      { A = feat2; Wt = Wvt; bias = bv; outp = Vtw; scale = 1.0f;    trans = 1; }

  __shared__ __align__(16) short As[64][72];    // A tile 64x64 bf16
  __shared__ __align__(16) short Ws[256][72];   // W tile 256x64 bf16

  int m0 = blockIdx.x * 64;
  int t = threadIdx.x;
  int w = t >> 6, L = t & 63, rowA = L & 15, quad = L >> 4;
  int ar = t >> 2, ac16 = (t & 3) * 16;   // A staging: 4 lanes/row

  f32x4 acc[4][4];
  for (int i = 0; i < 4; ++i)
    for (int j = 0; j < 4; ++j) acc[i][j] = (f32x4){0.f, 0.f, 0.f, 0.f};

  for (int k0 = 0; k0 < D_; k0 += 64) {
    {   // stage A 64x64 fp32->bf16: each thread 16 floats
      const float* src = A + (size_t)(m0 + ar) * D_ + k0 + ac16;
      f32x4 v0 = *(const f32x4*)(src);
      f32x4 v1 = *(const f32x4*)(src + 4);
      f32x4 v2 = *(const f32x4*)(src + 8);
      f32x4 v3 = *(const f32x4*)(src + 12);
      s16x8 s0, s1;
      ((int*)&s0)[0] = pk2bf(v0[0], v0[1]); ((int*)&s0)[1] = pk2bf(v0[2], v0[3]);
      ((int*)&s0)[2] = pk2bf(v1[0], v1[1]); ((int*)&s0)[3] = pk2bf(v1[2], v1[3]);
      ((int*)&s1)[0] = pk2bf(v2[0], v2[1]); ((int*)&s1)[1] = pk2bf(v2[2], v2[3]);
      ((int*)&s1)[2] = pk2bf(v3[0], v3[1]); ((int*)&s1)[3] = pk2bf(v3[2], v3[3]);
      *(s16x8*)(&As[ar][ac16]) = s0;
      *(s16x8*)(&As[ar][ac16 + 8]) = s1;
    }
    for (int p = 0; p < 4; ++p) {   // stage W 256x64: 4 passes of 64 rows
      int r = (t >> 2) + p * 64;
      const short* src = Wt + (size_t)r * D_ + k0 + ac16;
      *(s16x8*)(&Ws[r][ac16]) = *(const s16x8*)(src);
      *(s16x8*)(&Ws[r][ac16 + 8]) = *(const s16x8*)(src + 8);
    }
    __syncthreads();
    for (int kt = 0; kt < 2; ++kt) {
      s16x8 a[4];
      for (int mt = 0; mt < 4; ++mt)
        a[mt] = *(const s16x8*)(&As[mt * 16 + rowA][kt * 32 + quad * 8]);
      for (int nt = 0; nt < 4; ++nt) {
        s16x8 bfr = *(const s16x8*)(&Ws[w * 64 + nt * 16 + rowA][kt * 32 + quad * 8]);
        for (int mt = 0; mt < 4; ++mt)
          acc[mt][nt] = __builtin_amdgcn_mfma_f32_16x16x32_bf16(a[mt], bfr, acc[mt][nt], 0, 0, 0);
      }
    }
    __syncthreads();
  }

  if (!trans) {
    float bn[4];
    for (int nt = 0; nt < 4; ++nt) bn[nt] = bias[w * 64 + nt * 16 + rowA];
    for (int mt = 0; mt < 4; ++mt) {
      int m = m0 + mt * 16 + quad * 4;
      for (int nt = 0; nt < 4; ++nt) {
        int n = w * 64 + nt * 16 + rowA;
        for (int r = 0; r < 4; ++r)
          outp[(size_t)(m + r) * F_ + n] = f2bf((acc[mt][nt][r] + bn[nt]) * scale);
      }
    }
  } else {
    int bb = m0 >> 11;
    int tbase = m0 & (S2_ - 1);
    float bn[4];
    for (int nt = 0; nt < 4; ++nt) bn[nt] = bias[w * 64 + nt * 16 + rowA];
    for (int nt = 0; nt < 4; ++nt) {
      int f = w * 64 + nt * 16 + rowA;
      for (int mt = 0; mt < 4; ++mt) {
        int tt = tbase + mt * 16 + quad * 4;
        s16x4 o;
        for (int r = 0; r < 4; ++r) o[r] = f2bf(acc[mt][nt][r] + bn[nt]);
        *(s16x4*)(outp + ((size_t)bb * F_ + f) * S2_ + tt) = o;
      }
    }
  }
}

// ---------------- flash attention: wave-specialized + XCD swizzle ---------
// R8 verbatim (proven 58.4 us, FETCH 12.4 MB).
__global__ __launch_bounds__(512, 2) void flash_kernel(
    const short* __restrict__ Q,    // [B][S1][F] bf16 (scaled)
    const short* __restrict__ K,    // [B][S2][F] bf16
    const short* __restrict__ Vt,   // [B][F][S2] bf16
    short* __restrict__ O) {        // [B][S1][F] bf16 (normalized)
  __shared__ __align__(16) short Ks[2][64][264];   // 67584 B
  __shared__ __align__(16) short Vs[2][256][72];   // 73728 B
  __shared__ __align__(16) short Ps[2][64][72];    // 18432 B  (sum 159744)

  int b = blockIdx.x & 7;            // XCD-aware: batch = block % 8
  int s0 = (blockIdx.x >> 3) * 64;
  int t = threadIdx.x;
  int w = t >> 6, L = t & 63, rowA = L & 15, quad = L >> 4;
  int isS = (w < 4);

  const short* Kb = K + (size_t)b * S2_ * F_;
  const short* Vb = Vt + (size_t)b * F_ * S2_;

  int kr = t >> 5, kc8 = (t & 31) * 8;
  int vr = t >> 3, vc8 = (t & 7) * 8;

  int rs = (w & 1) * 32, cs = ((w >> 1) & 1) * 32;   // S-wave quadrant
  int mg = (w - 4) & 1, fg = ((w - 4) >> 1) & 1;     // PV-wave tile

  s16x8 qf[2][8];
  if (isS) {
    const short* Qb = Q + ((size_t)b * S1_ + s0 + rs) * F_;
    for (int mt = 0; mt < 2; ++mt)
      for (int kt = 0; kt < 8; ++kt)
        qf[mt][kt] = *(const s16x8*)(Qb + (size_t)(mt * 16 + rowA) * F_ + kt * 32 + quad * 8);
  }
  f32x4 o[2][8];
  for (int i = 0; i < 2; ++i)
    for (int j = 0; j < 8; ++j) o[i][j] = (f32x4){0.f, 0.f, 0.f, 0.f};
  float l_lane[2][4] = {{0.f,0.f,0.f,0.f},{0.f,0.f,0.f,0.f}};

  s16x8 kpre[4], vpre[4];
  for (int p = 0; p < 4; ++p)
    kpre[p] = *(const s16x8*)(Kb + (size_t)(kr + p * 16) * F_ + kc8);
  for (int p = 0; p < 4; ++p)
    *(s16x8*)(&Ks[0][kr + p * 16][kc8]) = kpre[p];
  for (int p = 0; p < 4; ++p)
    kpre[p] = *(const s16x8*)(Kb + (size_t)(64 + kr + p * 16) * F_ + kc8);
  for (int p = 0; p < 4; ++p)
    vpre[p] = *(const s16x8*)(Vb + (size_t)(vr + p * 64) * S2_ + vc8);

  for (int it = 0; it <= 32; ++it) {
    int cb = it & 1;
    __syncthreads();
    if (it < 32) {
      for (int p = 0; p < 4; ++p)
        *(s16x8*)(&Vs[cb][vr + p * 64][vc8]) = vpre[p];
      if (it < 31) {
        for (int p = 0; p < 4; ++p)
          *(s16x8*)(&Ks[1 - cb][kr + p * 16][kc8]) = kpre[p];
        int n0 = (it + 1) * 64;
        for (int p = 0; p < 4; ++p)
          vpre[p] = *(const s16x8*)(Vb + (size_t)(vr + p * 64) * S2_ + n0 + vc8);
      }
      if (it < 30) {
        int n0 = (it + 2) * 64;
        for (int p = 0; p < 4; ++p)
          kpre[p] = *(const s16x8*)(Kb + (size_t)(n0 + kr + p * 16) * F_ + kc8);
      }
    }
    if (isS) {
      if (it < 32) {
        f32x4 s[2][2];
        for (int i = 0; i < 2; ++i)
          for (int j = 0; j < 2; ++j) s[i][j] = (f32x4){0.f, 0.f, 0.f, 0.f};
        for (int kt = 0; kt < 8; ++kt) {
          s16x8 bf0 = *(const s16x8*)(&Ks[cb][cs + rowA][kt * 32 + quad * 8]);
          s16x8 bf1 = *(const s16x8*)(&Ks[cb][cs + 16 + rowA][kt * 32 + quad * 8]);
          for (int mt = 0; mt < 2; ++mt) {
            s[mt][0] = __builtin_amdgcn_mfma_f32_16x16x32_bf16(qf[mt][kt], bf0, s[mt][0], 0, 0, 0);
            s[mt][1] = __builtin_amdgcn_mfma_f32_16x16x32_bf16(qf[mt][kt], bf1, s[mt][1], 0, 0, 0);
          }
        }
        for (int mt = 0; mt < 2; ++mt)
          for (int nt = 0; nt < 2; ++nt)
            for (int r = 0; r < 4; ++r) {
              float p = __expf(s[mt][nt][r]);
              l_lane[mt][r] += p;
              Ps[cb][rs + mt * 16 + quad * 4 + r][cs + nt * 16 + rowA] = f2bf(p);
            }
      }
    } else {
      if (it > 0) {
        int pb = 1 - cb;
        s16x8 pa[2][2];
        for (int mt = 0; mt < 2; ++mt)
          for (int kt = 0; kt < 2; ++kt)
            pa[mt][kt] = *(const s16x8*)(&Ps[pb][mg * 32 + mt * 16 + rowA][kt * 32 + quad * 8]);
        for (int ft = 0; ft < 8; ++ft)
          for (int kt = 0; kt < 2; ++kt) {
            s16x8 vf = *(const s16x8*)(&Vs[pb][fg * 128 + ft * 16 + rowA][kt * 32 + quad * 8]);
            for (int mt = 0; mt < 2; ++mt)
              o[mt][ft] = __builtin_amdgcn_mfma_f32_16x16x32_bf16(pa[mt][kt], vf, o[mt][ft], 0, 0, 0);
          }
      }
    }
  }

  float* lf = (float*)&Ks[0][0][0];   // [2 col-halves][64 rows]
  if (isS) {
    for (int mt = 0; mt < 2; ++mt)
      for (int r = 0; r < 4; ++r) {
        float x = l_lane[mt][r];
        for (int off = 1; off < 16; off <<= 1)
          x += __shfl_xor(x, off, 64);
        if (rowA == 0)
          lf[((w >> 1) & 1) * 64 + rs + mt * 16 + quad * 4 + r] = x;
      }
  }
  __syncthreads();
  if (!isS) {
    short* Ob = O + ((size_t)b * S1_ + s0) * F_;
    for (int mt = 0; mt < 2; ++mt)
      for (int r = 0; r < 4; ++r) {
        int row = mg * 32 + mt * 16 + quad * 4 + r;
        float inv = 1.0f / (lf[row] + lf[64 + row]);
        for (int ft = 0; ft < 8; ++ft)
          Ob[(size_t)row * F_ + fg * 128 + ft * 16 + rowA] = f2bf(o[mt][ft][r] * inv);
      }
  }
}

// ---------------- FC: 64x128 tile, 512 blocks (2/CU), prefetched ----------
__global__ __launch_bounds__(256) void fc_kernel(
    const short* __restrict__ AO,   // [16384][256] bf16
    const short* __restrict__ Wt,   // [256 g][256 k] bf16
    const float* __restrict__ bias,
    float* __restrict__ out) {
  __shared__ __align__(16) short As[64][72];    // 9216 B
  __shared__ __align__(16) short Ws[128][72];   // 18432 B (27.6 KB total)

  int m0 = blockIdx.x * 64;
  int n0 = blockIdx.y * 128;
  int t = threadIdx.x;
  int w = t >> 6, L = t & 63, rowA = L & 15, quad = L >> 4;
  int wy = w & 1, wx = w >> 1;   // 32-row half, 64-col half

  int ar = t >> 2, ac16 = (t & 3) * 16;   // A staging: 16 shorts/thread
  int wr = t >> 1, wc32 = (t & 1) * 32;   // W staging: 32 shorts/thread

  s16x8 apre[2], wpre[4];
  {   // prologue k0 = 0
    const short* asrc = AO + (size_t)(m0 + ar) * F_ + ac16;
    apre[0] = *(const s16x8*)(asrc);
    apre[1] = *(const s16x8*)(asrc + 8);
    const short* wsrc = Wt + (size_t)(n0 + wr) * F_ + wc32;
    for (int j = 0; j < 4; ++j) wpre[j] = *(const s16x8*)(wsrc + j * 8);
  }

  f32x4 acc[2][4];
  for (int i = 0; i < 2; ++i)
    for (int j = 0; j < 4; ++j) acc[i][j] = (f32x4){0.f, 0.f, 0.f, 0.f};

  for (int k0 = 0; k0 < F_; k0 += 64) {
    *(s16x8*)(&As[ar][ac16]) = apre[0];
    *(s16x8*)(&As[ar][ac16 + 8]) = apre[1];
    for (int j = 0; j < 4; ++j) *(s16x8*)(&Ws[wr][wc32 + j * 8]) = wpre[j];
    __syncthreads();
    if (k0 + 64 < F_) {   // prefetch next slab
      const short* asrc = AO + (size_t)(m0 + ar) * F_ + k0 + 64 + ac16;
      apre[0] = *(const s16x8*)(asrc);
      apre[1] = *(const s16x8*)(asrc + 8);
      const short* wsrc = Wt + (size_t)(n0 + wr) * F_ + k0 + 64 + wc32;
      for (int j = 0; j < 4; ++j) wpre[j] = *(const s16x8*)(wsrc + j * 8);
    }
    for (int kt = 0; kt < 2; ++kt) {
      s16x8 a[2];
      for (int mt = 0; mt < 2; ++mt)
        a[mt] = *(const s16x8*)(&As[wy * 32 + mt * 16 + rowA][kt * 32 + quad * 8]);
      for (int nt = 0; nt < 4; ++nt) {
        s16x8 bfr = *(const s16x8*)(&Ws[wx * 64 + nt * 16 + rowA][kt * 32 + quad * 8]);
        for (int mt = 0; mt < 2; ++mt)
          acc[mt][nt] = __builtin_amdgcn_mfma_f32_16x16x32_bf16(a[mt], bfr, acc[mt][nt], 0, 0, 0);
      }
    }
    __syncthreads();
  }

  float bn[4];
  for (int nt = 0; nt < 4; ++nt) bn[nt] = bias[n0 + wx * 64 + nt * 16 + rowA];
  for (int mt = 0; mt < 2; ++mt) {
    int m = m0 + wy * 32 + mt * 16 + quad * 4;
    for (int nt = 0; nt < 4; ++nt) {
      int n = n0 + wx * 64 + nt * 16 + rowA;
      for (int r = 0; r < 4; ++r)
        out[(size_t)(m + r) * F_ + n] = acc[mt][nt][r] + bn[nt];
    }
  }
}

extern "C" void kernel_launch(void* const* d_in, const int* in_sizes, int n_in,
                              void* d_out, int out_size, void* d_ws, size_t ws_size,
                              hipStream_t stream) {
  const float* feat1 = (const float*)d_in[0];
  const float* feat2 = (const float*)d_in[1];
  const float* Wq  = (const float*)d_in[2];
  const float* bq  = (const float*)d_in[3];
  const float* Wk  = (const float*)d_in[4];
  const float* bk  = (const float*)d_in[5];
  const float* Wv  = (const float*)d_in[6];
  const float* bv  = (const float*)d_in[7];
  const float* Wfc = (const float*)d_in[8];
  const float* bfc = (const float*)d_in[9];
  float* out = (float*)d_out;
  char* ws = (char*)d_ws;

  // workspace layout: 32.75 MB total (proven-safe footprint)
  short* Qw   = (short*)(ws);                       // 8 MB  [B][S1][F]
  short* Kw   = (short*)(ws + (size_t)(8u  << 20)); // 8 MB  [B][S2][F]
  short* Vtw  = (short*)(ws + (size_t)(16u << 20)); // 8 MB  [B][F][S2]
  short* AOw  = (short*)(ws + (size_t)(24u << 20)); // 8 MB  [B][S1][F]
  short* Wqt  = (short*)(ws + (size_t)(32u << 20)); // 256KB [F][D]
  short* Wkt  = Wqt + 256 * 512;
  short* Wvt  = Wkt + 256 * 512;
  short* Wfct = Wvt + 256 * 512;                    // [256][256]

  wtrans_kernel<<<dim3(32, 4), 256, 0, stream>>>(Wq, Wk, Wv, Wfc, Wqt, Wkt, Wvt, Wfct);
  proj_kernel<<<dim3(256, 3), 256, 0, stream>>>(feat1, feat2, Wqt, Wkt, Wvt,
                                                bq, bk, bv, Qw, Kw, Vtw);
  flash_kernel<<<dim3(256), 512, 0, stream>>>(Qw, Kw, Vtw, AOw);
  fc_kernel<<<dim3(256, 2), 256, 0, stream>>>(AOw, Wfct, bfc, out);
}